// Round 2
// baseline (474.970 us; speedup 1.0000x reference)
//
#include <hip/hip_runtime.h>

#define NN 400000
#define NE 400000
#define HIDDIM 128
#define NHEADS 4

typedef __attribute__((ext_vector_type(4))) float f32x4;
typedef __attribute__((ext_vector_type(8))) short s16x8;

__device__ __forceinline__ unsigned short f2bf(float f) {
    union { float f; unsigned int u; } c;
    c.f = f;
    unsigned int u = c.u;
    u = u + 0x7fffu + ((u >> 16) & 1u);
    return (unsigned short)(u >> 16);
}

// --- detect whether edge_index arrived as int64 (odd 32-bit words all zero) ---
__global__ void k_detect(const int* __restrict__ ei_raw, int* __restrict__ flag) {
    if (threadIdx.x == 0 && blockIdx.x == 0) {
        int is64 = 1;
        for (int i = 0; i < 64; i++)
            if (ei_raw[2 * i + 1] != 0) { is64 = 0; break; }
        flag[0] = is64;
    }
}

// --- normalize edge_index to int32 (2*NE elements) ---
__global__ void k_cvt_idx(const int* __restrict__ ei_raw, const int* __restrict__ flag,
                          int* __restrict__ ei32) {
    const int i = blockIdx.x * 256 + threadIdx.x;  // i < 2*NE
    const int f = flag[0];
    ei32[i] = f ? ei_raw[2 * i] : ei_raw[i];
}

// --- convert W [128,512] f32 -> bf16 (row-major, same layout) ---
__global__ void k_wcvt(const float* __restrict__ W, unsigned short* __restrict__ wbf) {
    const int i = blockIdx.x * 256 + threadIdx.x;
    wbf[i] = f2bf(W[i]);
}

// --- per-node u,v: uv[n][0..3]=dot(x[n],att[h,:128]); uv[n][4..7]=dot(x[n],att[h,128:]) ---
__global__ void k_uv(const float* __restrict__ x, const float* __restrict__ att,
                     float* __restrict__ uv) {
    const int lane = threadIdx.x & 63;
    const int n = blockIdx.x * 4 + (threadIdx.x >> 6);
    const float2 x2 = *(const float2*)(x + (size_t)n * HIDDIM + 2 * lane);
    float r[8];
#pragma unroll
    for (int h = 0; h < 4; h++) {
        const float2 af = *(const float2*)(att + h * 256 + 2 * lane);
        const float2 ab = *(const float2*)(att + h * 256 + 128 + 2 * lane);
        r[h]     = x2.x * af.x + x2.y * af.y;
        r[4 + h] = x2.x * ab.x + x2.y * ab.y;
    }
#pragma unroll
    for (int m = 32; m >= 1; m >>= 1) {
#pragma unroll
        for (int j = 0; j < 8; j++) r[j] += __shfl_xor(r[j], m, 64);
    }
    if (lane == 0) {
        f32x4 a, bv;
#pragma unroll
        for (int h = 0; h < 4; h++) { a[h] = r[h]; bv[h] = r[4 + h]; }
        *(f32x4*)(uv + (size_t)n * 8) = a;
        *(f32x4*)(uv + (size_t)n * 8 + 4) = bv;
    }
}

// --- per-edge: leaky_relu -> head softmax -> p=exp(score), atomic denom per (row,head) ---
__global__ void k_edge(const int* __restrict__ ei, const float* __restrict__ uv,
                       float* __restrict__ p, float* __restrict__ denom) {
    const int e = blockIdx.x * 256 + threadIdx.x;
    if (e >= NE) return;
    const int row = ei[e];
    const int col = ei[NE + e];
    const f32x4 u = *(const f32x4*)(uv + (size_t)row * 8);
    const f32x4 v = *(const f32x4*)(uv + (size_t)col * 8 + 4);
    float s[4];
    float mx = -1e30f;
#pragma unroll
    for (int h = 0; h < 4; h++) {
        float t = u[h] + v[h];
        t = t > 0.f ? t : 0.01f * t;
        s[h] = t;
        mx = fmaxf(mx, t);
    }
    float ex[4], sum = 0.f;
#pragma unroll
    for (int h = 0; h < 4; h++) { ex[h] = __expf(s[h] - mx); sum += ex[h]; }
    const float inv = 1.f / sum;
    f32x4 pv;
#pragma unroll
    for (int h = 0; h < 4; h++) pv[h] = __expf(ex[h] * inv);
    *(f32x4*)(p + (size_t)e * 4) = pv;
#pragma unroll
    for (int h = 0; h < 4; h++) atomicAdd(denom + (size_t)row * 4 + h, pv[h]);
}

// --- alpha[e,h] = p[e,h] / denom[row[e],h] ---
__global__ void k_alpha(const int* __restrict__ ei, const float* __restrict__ p,
                        const float* __restrict__ denom, float* __restrict__ alpha) {
    const int t = blockIdx.x * 256 + threadIdx.x;  // t < NE*4
    const int e = t >> 2, h = t & 3;
    const int row = ei[e];
    alpha[t] = p[t] / denom[row * 4 + h];
}

// --- GEMM: out[e,i] = sum_k A[e,k] * W[i,k] + b[i] + x[e,i]
//     A[e, h*128+j] = alpha[e,h] * x[col[e], j]
//     tile: 64 edges x 128 cols, BK=64 (2 MFMA k-subchunks of 32!),
//     4 waves (2x2), MFMA 16x16x32 bf16 ---
__global__ __launch_bounds__(256) void k_gemm(
    const float* __restrict__ x, const int* __restrict__ ei,
    const float* __restrict__ alpha, const unsigned short* __restrict__ wbf,
    const float* __restrict__ bias, float* __restrict__ out)
{
    __shared__ __align__(16) unsigned short Asm[64 * 64];    // [edge][k] bf16, XOR-swizzled
    __shared__ __align__(16) unsigned short Bsm[128 * 64];   // [outcol][k] bf16, XOR-swizzled
    __shared__ float alpha_s[256];
    __shared__ int col_s[64];

    const int tid = threadIdx.x;
    const int e0 = blockIdx.x * 64;
    const int lane = tid & 63;
    const int wid = tid >> 6;
    const int wr = wid >> 1;   // edge half (32 edges)
    const int wc = wid & 1;    // col half (64 cols)

    if (tid < 64) col_s[tid] = ei[NE + e0 + tid];
    alpha_s[tid] = alpha[e0 * 4 + tid];

    f32x4 acc[2][4];
#pragma unroll
    for (int a = 0; a < 2; a++)
#pragma unroll
        for (int c = 0; c < 4; c++) acc[a][c] = {0.f, 0.f, 0.f, 0.f};

    const int e_loc = tid >> 2;   // A-stage: 4 threads per edge
    const int part  = tid & 3;
    const int brow  = tid >> 1;   // B-stage: 2 threads per W row
    const int bhalf = tid & 1;

    for (int ks = 0; ks < 8; ks++) {
        const int k0g = ks * 64;
        const int h   = ks >> 1;
        const int j0  = (ks & 1) * 64;
        __syncthreads();
        // A stage: gather x[col], scale by alpha[e,h], cvt bf16, swizzled ds_write
        {
            const float* xr = x + (size_t)col_s[e_loc] * HIDDIM + j0 + part * 16;
            const float av = alpha_s[e_loc * 4 + h];
#pragma unroll
            for (int q = 0; q < 2; q++) {
                const f32x4 v0 = *(const f32x4*)(xr + q * 8);
                const f32x4 v1 = *(const f32x4*)(xr + q * 8 + 4);
                s16x8 pk;
#pragma unroll
                for (int m = 0; m < 4; m++) pk[m] = (short)f2bf(v0[m] * av);
#pragma unroll
                for (int m = 0; m < 4; m++) pk[4 + m] = (short)f2bf(v1[m] * av);
                const int kbyte = (part * 16 + q * 8) * 2;
                const int byte = (e_loc * 128 + kbyte) ^ ((e_loc & 7) << 4);
                *(s16x8*)((char*)Asm + byte) = pk;
            }
        }
        // B stage: linear bf16 loads of W rows, swizzled ds_write
        {
            const unsigned short* src = wbf + brow * 512 + k0g + bhalf * 32;
#pragma unroll
            for (int q = 0; q < 4; q++) {
                const s16x8 pk = *(const s16x8*)(src + q * 8);
                const int kbyte = (bhalf * 32 + q * 8) * 2;
                const int byte = (brow * 128 + kbyte) ^ ((brow & 7) << 4);
                *(s16x8*)((char*)Bsm + byte) = pk;
            }
        }
        __syncthreads();
        // fragments + MFMA: BK=64 -> two k-subchunks of 32 per MFMA shape
        s16x8 afr[2][2], bfr[2][4];
#pragma unroll
        for (int ksub = 0; ksub < 2; ksub++) {
#pragma unroll
            for (int eb = 0; eb < 2; eb++) {
                const int row = wr * 32 + eb * 16 + (lane & 15);
                const int byte = (row * 128 + ksub * 64 + (lane >> 4) * 16) ^ ((row & 7) << 4);
                afr[ksub][eb] = *(const s16x8*)((const char*)Asm + byte);
            }
#pragma unroll
            for (int ib = 0; ib < 4; ib++) {
                const int row = wc * 64 + ib * 16 + (lane & 15);
                const int byte = (row * 128 + ksub * 64 + (lane >> 4) * 16) ^ ((row & 7) << 4);
                bfr[ksub][ib] = *(const s16x8*)((const char*)Bsm + byte);
            }
        }
#pragma unroll
        for (int ksub = 0; ksub < 2; ksub++)
#pragma unroll
            for (int eb = 0; eb < 2; eb++)
#pragma unroll
                for (int ib = 0; ib < 4; ib++)
                    acc[eb][ib] = __builtin_amdgcn_mfma_f32_16x16x32_bf16(
                        afr[ksub][eb], bfr[ksub][ib], acc[eb][ib], 0, 0, 0);
    }

    // epilogue: + bias + x[e] (residual), coalesced
#pragma unroll
    for (int ib = 0; ib < 4; ib++) {
        const int i = wc * 64 + ib * 16 + (lane & 15);
        const float bb = bias[i];
#pragma unroll
        for (int eb = 0; eb < 2; eb++) {
#pragma unroll
            for (int r = 0; r < 4; r++) {
                const int e = e0 + wr * 32 + eb * 16 + (lane >> 4) * 4 + r;
                const size_t off = (size_t)e * HIDDIM + i;
                out[off] = acc[eb][ib][r] + bb + x[off];
            }
        }
    }
}

extern "C" void kernel_launch(void* const* d_in, const int* in_sizes, int n_in,
                              void* d_out, int out_size, void* d_ws, size_t ws_size,
                              hipStream_t stream) {
    const float* x      = (const float*)d_in[0];
    const int*   ei_raw = (const int*)d_in[1];  // [2,E] flat: rows then cols (int32 or int64)
    const float* att    = (const float*)d_in[2];  // [1,4,256]
    const float* W      = (const float*)d_in[3];  // [128,512]
    const float* b      = (const float*)d_in[4];  // [128]
    float* out = (float*)d_out;

    char* ws = (char*)d_ws;
    float*          uv    = (float*)(ws);                     // N*8 f32   = 12.8 MB
    float*          p     = (float*)(ws + 12800000);          // E*4 f32   =  6.4 MB
    float*          denom = (float*)(ws + 19200000);          // N*4 f32   =  6.4 MB
    float*          alpha = (float*)(ws + 25600000);          // E*4 f32   =  6.4 MB
    unsigned short* wbf   = (unsigned short*)(ws + 32000000); // 128 KB
    int*            flag  = (int*)(ws + 32200000);            // 4 B
    int*            ei32  = (int*)(ws + 32200064);            // 2*E int32 = 3.2 MB

    hipMemsetAsync(denom, 0, (size_t)NN * 4 * sizeof(float), stream);
    k_detect<<<1, 64, 0, stream>>>(ei_raw, flag);
    k_cvt_idx<<<2 * NE / 256, 256, 0, stream>>>(ei_raw, flag, ei32);
    k_wcvt<<<256, 256, 0, stream>>>(W, wbf);
    k_uv<<<NN / 4, 256, 0, stream>>>(x, att, uv);
    k_edge<<<(NE + 255) / 256, 256, 0, stream>>>(ei32, uv, p, denom);
    k_alpha<<<NE * 4 / 256, 256, 0, stream>>>(ei32, p, denom, alpha);
    k_gemm<<<NE / 64, 256, 0, stream>>>(x, ei32, alpha, wbf, b, out);
}

// Round 3
// 310.424 us; speedup vs baseline: 1.5301x; 1.5301x over previous
//
#include <hip/hip_runtime.h>

#define NN 400000
#define NE 400000

typedef __attribute__((ext_vector_type(4))) float f32x4;
typedef __attribute__((ext_vector_type(8))) short s16x8;
typedef unsigned short ushort_t;

__device__ __forceinline__ ushort_t f2bf(float f) {
    union { float f; unsigned int u; } c;
    c.f = f;
    unsigned int u = c.u;
    u = u + 0x7fffu + ((u >> 16) & 1u);
    return (ushort_t)(u >> 16);
}
__device__ __forceinline__ float bf2f(ushort_t v) {
    union { unsigned int u; float f; } c;
    c.u = ((unsigned int)v) << 16;
    return c.f;
}

// --- detect whether edge_index arrived as int64 (odd 32-bit words all zero) ---
__global__ void k_detect(const int* __restrict__ ei_raw, int* __restrict__ flag) {
    if (threadIdx.x == 0 && blockIdx.x == 0) {
        int is64 = 1;
        for (int i = 0; i < 64; i++)
            if (ei_raw[2 * i + 1] != 0) { is64 = 0; break; }
        flag[0] = is64;
    }
}

__global__ void k_cvt_idx(const int* __restrict__ ei_raw, const int* __restrict__ flag,
                          int* __restrict__ ei32) {
    const int i = blockIdx.x * 256 + threadIdx.x;
    const int f = flag[0];
    ei32[i] = f ? ei_raw[2 * i] : ei_raw[i];
}

// --- W -> bf16, permuted + pre-swizzled so linear global_load_lds + swizzled
//     ds_read yields B_h[i][j] = W[i, h*128+j]. Chunk c = h*2+half (8KB ushorts each):
//     LDS byte L: i=L>>7, inner=L&127, koff=inner^((i&7)<<4), j=half*64+koff/2.
__global__ void k_wcvt(const float* __restrict__ W, ushort_t* __restrict__ wsw) {
    const int t = blockIdx.x * 256 + threadIdx.x;    // 0..65535
    const int c = t >> 13;
    const int h = c >> 1, half = c & 1;
    const int si = t & 8191;
    const int i = si >> 6;
    const int inner = (si * 2) & 127;
    const int koff = inner ^ ((i & 7) << 4);
    const int j = half * 64 + (koff >> 1);
    wsw[t] = f2bf(W[i * 512 + h * 128 + j]);
}

// --- fused: per-node u,v scores + x -> bf16 conversion.
//     16 lanes/node, att in registers (8 elems/lane), 2 nodes per lane per iter ---
__global__ void k_uv_cvt(const float* __restrict__ x, const float* __restrict__ att,
                         ushort_t* __restrict__ xbf, float* __restrict__ uv) {
    const int lane = threadIdx.x & 63;
    const int wid = threadIdx.x >> 6;
    const int g = lane & 15;      // element group: elems g*8..g*8+8
    const int ns = lane >> 4;     // node slot within wave

    float areg[8][8];             // [v][m]: v<4 front (dst), v>=4 back (src)
#pragma unroll
    for (int h = 0; h < 4; h++) {
        const f32x4 fa = *(const f32x4*)(att + h * 256 + g * 8);
        const f32x4 fb = *(const f32x4*)(att + h * 256 + g * 8 + 4);
        const f32x4 ba = *(const f32x4*)(att + h * 256 + 128 + g * 8);
        const f32x4 bb = *(const f32x4*)(att + h * 256 + 128 + g * 8 + 4);
#pragma unroll
        for (int m = 0; m < 4; m++) {
            areg[h][m] = fa[m];     areg[h][4 + m] = fb[m];
            areg[4 + h][m] = ba[m]; areg[4 + h][4 + m] = bb[m];
        }
    }

    for (int tile = blockIdx.x; tile < NN / 32; tile += gridDim.x) {
        const int nb = tile * 32 + wid * 8 + ns;
#pragma unroll
        for (int t = 0; t < 2; t++) {
            const int n = nb + t * 4;
            const f32x4 xa = *(const f32x4*)(x + (size_t)n * 128 + g * 8);
            const f32x4 xb = *(const f32x4*)(x + (size_t)n * 128 + g * 8 + 4);
            s16x8 pk;
#pragma unroll
            for (int m = 0; m < 4; m++) { pk[m] = (short)f2bf(xa[m]); pk[4 + m] = (short)f2bf(xb[m]); }
            *(s16x8*)(xbf + (size_t)n * 128 + g * 8) = pk;
            float r[8];
#pragma unroll
            for (int v = 0; v < 8; v++) {
                float s = 0.f;
#pragma unroll
                for (int m = 0; m < 4; m++) s += xa[m] * areg[v][m];
#pragma unroll
                for (int m = 0; m < 4; m++) s += xb[m] * areg[v][4 + m];
                r[v] = s;
            }
#pragma unroll
            for (int mask = 1; mask <= 4; mask <<= 1)
#pragma unroll
                for (int v = 0; v < 8; v++) r[v] += __shfl_xor(r[v], mask, 64);
            const int gv = g & 7;
            float s = r[0];
#pragma unroll
            for (int v = 1; v < 8; v++) s = (gv == v) ? r[v] : s;
            s += __shfl_xor(s, 8, 64);
            if (g < 8) uv[(size_t)n * 8 + g] = s;
        }
    }
}

// --- per-edge: leaky_relu -> head softmax -> p=exp(score), atomic denom ---
__global__ void k_edge(const int* __restrict__ ei, const float* __restrict__ uv,
                       float* __restrict__ p, float* __restrict__ denom) {
    const int e = blockIdx.x * 256 + threadIdx.x;
    if (e >= NE) return;
    const int row = ei[e];
    const int col = ei[NE + e];
    const f32x4 u = *(const f32x4*)(uv + (size_t)row * 8);
    const f32x4 v = *(const f32x4*)(uv + (size_t)col * 8 + 4);
    float s[4];
    float mx = -1e30f;
#pragma unroll
    for (int h = 0; h < 4; h++) {
        float t = u[h] + v[h];
        t = t > 0.f ? t : 0.01f * t;
        s[h] = t;
        mx = fmaxf(mx, t);
    }
    float ex[4], sum = 0.f;
#pragma unroll
    for (int h = 0; h < 4; h++) { ex[h] = __expf(s[h] - mx); sum += ex[h]; }
    const float inv = 1.f / sum;
    f32x4 pv;
#pragma unroll
    for (int h = 0; h < 4; h++) pv[h] = __expf(ex[h] * inv);
    *(f32x4*)(p + (size_t)e * 4) = pv;
#pragma unroll
    for (int h = 0; h < 4; h++) atomicAdd(denom + (size_t)row * 4 + h, pv[h]);
}

// --- alpha_t[h][e] = p[e,h] / denom[row[e],h]  (transposed planes) ---
__global__ void k_alpha(const int* __restrict__ ei, const float* __restrict__ p,
                        const float* __restrict__ denom, float* __restrict__ alpha_t) {
    const int e = blockIdx.x * 256 + threadIdx.x;
    if (e >= NE) return;
    const int row = ei[e];
    const f32x4 pv = *(const f32x4*)(p + (size_t)e * 4);
    const f32x4 dv = *(const f32x4*)(denom + (size_t)row * 4);
#pragma unroll
    for (int h = 0; h < 4; h++) alpha_t[(size_t)h * NE + e] = pv[h] / dv[h];
}

// --- head-split GEMM: for each head h, acc_h = Xcol_tile @ W_h^T (K=128, bf16 MFMA),
//     fin += alpha[e,h] * acc_h; out = fin + bias + x[e].
//     128 edges x 128 cols, 8 waves (4x2), A staged once, B double-buffered
//     via global_load_lds from pre-swizzled wsw. LDS = 32K + 2*16K = 64K. ---
__global__ __launch_bounds__(512) void k_gemm(
    const ushort_t* __restrict__ xbf, const int* __restrict__ ei,
    const float* __restrict__ alpha_t, const ushort_t* __restrict__ wsw,
    const float* __restrict__ bias, float* __restrict__ out)
{
    __shared__ __align__(16) ushort_t Asm[128 * 128];    // [e][j] bf16, 256B rows, swz ((e&7)<<4)
    __shared__ __align__(16) ushort_t Bsm[2][128 * 64];  // [buf][i][j-half] bf16, 128B rows, swz

    const int tid = threadIdx.x;
    const int lane = tid & 63;
    const int wid = tid >> 6;
    const int wr = wid >> 1;    // 0..3: edge rows wr*32..+32
    const int wc = wid & 1;     // 0..1: cols wc*64..+64
    const int e0 = blockIdx.x * 128;

#define B_ISSUE(c, buf) do {                                                         \
    const ushort_t* base_ = wsw + (c) * 8192;                                        \
    _Pragma("unroll")                                                                \
    for (int sub_ = 0; sub_ < 2; sub_++) {                                           \
        const int woff_ = wid * 2048 + sub_ * 1024;                                  \
        __builtin_amdgcn_global_load_lds(                                            \
            (const __attribute__((address_space(1))) unsigned int*)(base_ + woff_ / 2 + lane * 8), \
            (__attribute__((address_space(3))) unsigned int*)((char*)Bsm[buf] + woff_), \
            16, 0, 0);                                                               \
    } } while (0)

    // A stage: gather bf16 rows once (reg-staged, swizzled ds_write)
    {
        const int e_loc = tid >> 2, part = tid & 3;
        const int col = ei[NE + e0 + e_loc];
        const ushort_t* src = xbf + (size_t)col * 128 + part * 32;
#pragma unroll
        for (int q = 0; q < 4; q++) {
            const s16x8 v = *(const s16x8*)(src + q * 8);
            const int byte = (e_loc * 256 + part * 64 + q * 16) ^ ((e_loc & 7) << 4);
            *(s16x8*)((char*)Asm + byte) = v;
        }
    }
    B_ISSUE(0, 0);
    __syncthreads();   // A ready + B chunk0 landed (vmcnt drained)

    // A fragments, held across all heads: afr[jq][eb], j = jq*32 + (lane>>4)*8
    s16x8 afr[4][2];
#pragma unroll
    for (int jq = 0; jq < 4; jq++)
#pragma unroll
        for (int eb = 0; eb < 2; eb++) {
            const int row = wr * 32 + eb * 16 + (lane & 15);
            const int byte = (row * 256 + jq * 64 + (lane >> 4) * 16) ^ ((row & 7) << 4);
            afr[jq][eb] = *(const s16x8*)((const char*)Asm + byte);
        }

    f32x4 fin[2][4];
#pragma unroll
    for (int eb = 0; eb < 2; eb++)
#pragma unroll
        for (int ib = 0; ib < 4; ib++) fin[eb][ib] = {0.f, 0.f, 0.f, 0.f};

#pragma unroll
    for (int h = 0; h < 4; h++) {
        f32x4 acc[2][4];
#pragma unroll
        for (int half = 0; half < 2; half++) {
            const int c = h * 2 + half;
            if (c < 7) B_ISSUE(c + 1, (c + 1) & 1);
#pragma unroll
            for (int ks = 0; ks < 2; ks++) {
                const int jq = half * 2 + ks;
#pragma unroll
                for (int ib = 0; ib < 4; ib++) {
                    const int row = wc * 64 + ib * 16 + (lane & 15);
                    const int byte = (row * 128 + ks * 64 + (lane >> 4) * 16) ^ ((row & 7) << 4);
                    const s16x8 bfr = *(const s16x8*)((const char*)Bsm[c & 1] + byte);
#pragma unroll
                    for (int eb = 0; eb < 2; eb++) {
                        if (jq == 0)
                            acc[eb][ib] = __builtin_amdgcn_mfma_f32_16x16x32_bf16(
                                afr[0][eb], bfr, (f32x4){0.f, 0.f, 0.f, 0.f}, 0, 0, 0);
                        else
                            acc[eb][ib] = __builtin_amdgcn_mfma_f32_16x16x32_bf16(
                                afr[jq][eb], bfr, acc[eb][ib], 0, 0, 0);
                    }
                }
            }
            __syncthreads();   // drains my c+1 loads; all waves done reading buf c
        }
        // fin += alpha[e,h] * acc_h  (alpha_t plane: coalesced-ish b128 global)
#pragma unroll
        for (int eb = 0; eb < 2; eb++) {
            const int ebase = wr * 32 + eb * 16 + (lane >> 4) * 4;
            const f32x4 av = *(const f32x4*)(alpha_t + (size_t)h * NE + e0 + ebase);
#pragma unroll
            for (int ib = 0; ib < 4; ib++)
#pragma unroll
                for (int r = 0; r < 4; r++) fin[eb][ib][r] += av[r] * acc[eb][ib][r];
        }
    }

    // epilogue: + bias + residual (bf16 x)
#pragma unroll
    for (int ib = 0; ib < 4; ib++) {
        const int i = wc * 64 + ib * 16 + (lane & 15);
        const float bb = bias[i];
#pragma unroll
        for (int eb = 0; eb < 2; eb++) {
#pragma unroll
            for (int r = 0; r < 4; r++) {
                const int e = e0 + wr * 32 + eb * 16 + (lane >> 4) * 4 + r;
                const size_t off = (size_t)e * 128 + i;
                out[off] = fin[eb][ib][r] + bb + bf2f(xbf[off]);
            }
        }
    }
#undef B_ISSUE
}

extern "C" void kernel_launch(void* const* d_in, const int* in_sizes, int n_in,
                              void* d_out, int out_size, void* d_ws, size_t ws_size,
                              hipStream_t stream) {
    const float* x      = (const float*)d_in[0];
    const int*   ei_raw = (const int*)d_in[1];
    const float* att    = (const float*)d_in[2];
    const float* W      = (const float*)d_in[3];
    const float* b      = (const float*)d_in[4];
    float* out = (float*)d_out;

    char* ws = (char*)d_ws;
    float*    uv      = (float*)(ws);                     // N*8 f32   = 12.8 MB
    float*    p       = (float*)(ws + 12800000);          // E*4 f32   =  6.4 MB
    float*    denom   = (float*)(ws + 19200000);          // N*4 f32   =  6.4 MB
    float*    alpha_t = (float*)(ws + 25600000);          // 4 planes  =  6.4 MB
    ushort_t* wsw     = (ushort_t*)(ws + 32000000);       // 128 KB
    int*      flag    = (int*)(ws + 32200000);            // 4 B
    int*      ei32    = (int*)(ws + 32200064);            // 3.2 MB
    ushort_t* xbf     = (ushort_t*)(ws + 35400192);       // N*128 bf16 = 102.4 MB

    hipMemsetAsync(denom, 0, (size_t)NN * 4 * sizeof(float), stream);
    k_detect<<<1, 64, 0, stream>>>(ei_raw, flag);
    k_cvt_idx<<<2 * NE / 256, 256, 0, stream>>>(ei_raw, flag, ei32);
    k_wcvt<<<256, 256, 0, stream>>>(W, wsw);
    k_uv_cvt<<<2048, 256, 0, stream>>>(x, att, xbf, uv);
    k_edge<<<(NE + 255) / 256, 256, 0, stream>>>(ei32, uv, p, denom);
    k_alpha<<<(NE + 255) / 256, 256, 0, stream>>>(ei32, p, denom, alpha_t);
    k_gemm<<<NE / 128, 512, 0, stream>>>(xbf, ei32, alpha_t, wsw, b, out);
}